// Round 15
// baseline (113.034 us; speedup 1.0000x reference)
//
#include <hip/hip_runtime.h>

typedef unsigned short u16;
typedef unsigned u32;
typedef __bf16 bf16x8 __attribute__((ext_vector_type(8)));
typedef float f32x4 __attribute__((ext_vector_type(4)));
typedef u16 u16x8 __attribute__((ext_vector_type(8)));
typedef u16 u16x4v __attribute__((ext_vector_type(4)));

#define D_MODEL 1024
#define SEQ 2048
#define NB 2
#define NH 16

#define MFMA(a, b, c) __builtin_amdgcn_mfma_f32_16x16x32_bf16(a, b, c, 0, 0, 0)

__device__ __forceinline__ u16 f2bf(float f) {
  unsigned u = __builtin_bit_cast(unsigned, f);
  u += 0x7FFFu + ((u >> 16) & 1u);   // round-to-nearest-even
  return (u16)(u >> 16);
}

__device__ __forceinline__ u16 f2bf_hw(float f) {
  return __builtin_bit_cast(u16, (__bf16)f);
}

__device__ __forceinline__ bf16x8 ld8(const u16* p) {
  return __builtin_bit_cast(bf16x8, *(const u16x8*)p);
}

typedef const __attribute__((address_space(1))) unsigned gu32;
typedef __attribute__((address_space(3))) unsigned lu32;
__device__ __forceinline__ void gload16(const u16* g, u16* l) {
  // async global->LDS, 16B per lane; LDS dest = wave-uniform base + lane*16
  __builtin_amdgcn_global_load_lds((gu32*)g, (lu32*)l, 16, 0, 0);
}

#define WAITV8 asm volatile("s_waitcnt vmcnt(8)" ::: "memory")
#define WAITV4 asm volatile("s_waitcnt vmcnt(4)" ::: "memory")
#define WAITV0 asm volatile("s_waitcnt vmcnt(0)" ::: "memory")
#define BARRIER __builtin_amdgcn_s_barrier()
#define SB0 __builtin_amdgcn_sched_barrier(0)

// ---------------------------------------------------------------------------
// Kernel 0: fp32 -> bf16 convert of X and all four weight matrices.
// ---------------------------------------------------------------------------
__global__ __launch_bounds__(256) void convert_kernel(
    const float* __restrict__ X, const float* __restrict__ Wq,
    const float* __restrict__ Wk, const float* __restrict__ Wv,
    const float* __restrict__ Wo, u16* __restrict__ Xb, u16* __restrict__ Wb)
{
  const int NX4 = 1024 * 1024;
  const int NW4 = 256 * 1024;
  const int TOT = NX4 + 4 * NW4;
  for (int i = blockIdx.x * 256 + threadIdx.x; i < TOT; i += gridDim.x * 256) {
    const float* src;
    u16* dst;
    if (i < NX4) {
      src = X + (size_t)i * 4;
      dst = Xb + (size_t)i * 4;
    } else {
      int j = i - NX4;
      int w = j >> 18;
      int off = j & (NW4 - 1);
      const float* ws = (w == 0) ? Wq : (w == 1) ? Wk : (w == 2) ? Wv : Wo;
      src = ws + (size_t)off * 4;
      dst = Wb + (size_t)j * 4;
    }
    float4 v = *(const float4*)src;
    u16x4v o = { f2bf(v.x), f2bf(v.y), f2bf(v.z), f2bf(v.w) };
    *(u16x4v*)dst = o;
  }
}

// ---------------------------------------------------------------------------
// Kernel 1: QKV GEMM, 256x256 tile, 8 waves, BK=32, 4-buffer LDS rotation,
// one raw s_barrier per phase, counted vmcnt(8), compact-region XCD swizzle
// (unchanged from R14 — measured improvement).
// ---------------------------------------------------------------------------
__global__ __launch_bounds__(512, 2) void qkv8w(
    const u16* __restrict__ A, const u16* __restrict__ B,
    u16* __restrict__ Qb, u16* __restrict__ Kb, u16* __restrict__ Vt)
{
  __shared__ u16 As[4][8192];   // 4 x 16 KB
  __shared__ u16 Bs[4][8192];   // 4 x 16 KB  -> 128 KB total
  const int t = threadIdx.x;
  const int lane = t & 63, w = t >> 6;
  const int wm = w >> 2, wn = w & 3;

  // compact-region XCD swizzle: XCD = lid%8 -> 4x6 block region
  const int lid = blockIdx.x + 16 * blockIdx.y;   // 0..191
  const int xcd = lid & 7;
  const int k = lid >> 3;                          // 0..23
  const int bx = (xcd >> 1) * 4 + (k & 3);         // 0..15
  const int by = (xcd & 1) * 6 + (k >> 2);         // 0..11

  const int m0 = bx * 256;
  const int kg = lane >> 4, lr = lane & 15;
  const int rp = lr >> 1, hf = lr & 1;
  const int xr = (((hf * 4 + kg) ^ rp) * 8);

  const int lc = (lane & 7) ^ (lane >> 3);
  const int ghalf = lc >> 2, kc = lc & 3;
  const int n0 = by * 256;

  f32x4 acc[8][4] = {};

  auto stage = [&](int buf, int kt) {
    #pragma unroll
    for (int j = 0; j < 2; ++j) {
      int g = (j * 64 + w * 8 + (lane >> 3)) * 2 + ghalf;
      gload16(&A[(size_t)(m0 + g) * 1024 + kt * 32 + kc * 8],
              &As[buf][(j * 8 + w) * 512]);
      gload16(&B[(size_t)(n0 + g) * 1024 + kt * 32 + kc * 8],
              &Bs[buf][(j * 8 + w) * 512]);
    }
  };

  auto phase = [&](int buf) {
    const u16* as = &As[buf][0];
    const u16* bs = &Bs[buf][0];
    bf16x8 a[8], b[4];
    #pragma unroll
    for (int mi = 0; mi < 8; ++mi)
      a[mi] = ld8(&as[(wm * 64 + mi * 8 + rp) * 64 + xr]);
    #pragma unroll
    for (int ni = 0; ni < 4; ++ni)
      b[ni] = ld8(&bs[(wn * 32 + ni * 8 + rp) * 64 + xr]);
    __builtin_amdgcn_s_setprio(1);
    #pragma unroll
    for (int mi = 0; mi < 8; ++mi)
      #pragma unroll
      for (int ni = 0; ni < 4; ++ni)
        acc[mi][ni] = MFMA(a[mi], b[ni], acc[mi][ni]);
    __builtin_amdgcn_s_setprio(0);
  };

  stage(0, 0);
  stage(1, 1);
  stage(2, 2);

  for (int tt = 0; tt < 28; tt += 4) {
    #pragma unroll
    for (int q = 0; q < 4; ++q) {
      const int kt = tt + q;
      WAITV8;
      BARRIER;
      SB0;
      stage((q + 3) & 3, kt + 3);
      phase(q);
    }
  }
  WAITV8; BARRIER; SB0; stage(3, 31); phase(0);
  WAITV8; BARRIER; SB0; phase(1);
  WAITV4; BARRIER; SB0; phase(2);
  WAITV0; BARRIER; SB0; phase(3);

  // epilogue: scatter to Q/K/V.  C/D frag: row = kg*4+i, col = lr.
  const int zby = by >> 2;              // 0=Q, 1=K, 2=V
  const int nl0 = (by & 3) * 256;
  const float scl = (zby == 0) ? 0.125f : 1.0f; // fold 1/sqrt(d_k) into Q
  #pragma unroll
  for (int mi = 0; mi < 8; ++mi) {
    #pragma unroll
    for (int ni = 0; ni < 4; ++ni) {
      int m = m0 + wm * 128 + mi * 16 + kg * 4;
      int nl = nl0 + wn * 64 + ni * 16 + lr;
      int bb = m >> 11, s = m & (SEQ - 1);
      int h = nl >> 6, dk = nl & 63;
      size_t bh = (size_t)(bb * NH + h);
      if (zby == 2) {
        u16x4v v = { f2bf(acc[mi][ni][0]), f2bf(acc[mi][ni][1]),
                     f2bf(acc[mi][ni][2]), f2bf(acc[mi][ni][3]) };
        *(u16x4v*)&Vt[(bh * 64 + dk) * SEQ + s] = v;
      } else {
        u16* dst = (zby == 0 ? Qb : Kb) + ((bh * SEQ + s) * 64 + dk);
        #pragma unroll
        for (int i = 0; i < 4; ++i) dst[(size_t)i * 64] = f2bf(acc[mi][ni][i] * scl);
      }
    }
  }
}

// ---------------------------------------------------------------------------
// Kernel 3: output projection, 128x128-tile 2-phase GEMM (unchanged).
// ---------------------------------------------------------------------------
__global__ __launch_bounds__(256) void oproj_kernel(
    const u16* __restrict__ A, const u16* __restrict__ B,
    float* __restrict__ out)
{
  __shared__ u16 As[2][128 * 64];
  __shared__ u16 Bs[2][128 * 64];
  const int t = threadIdx.x;
  const int lane = t & 63, w = t >> 6;
  const int wr = w >> 1, wc = w & 1;
  const int m0 = blockIdx.x * 128;
  const int n0 = blockIdx.y * 128;
  const int kg = lane >> 4, lr = lane & 15;
  const int lrow = lane >> 3, lch = lane & 7;

  f32x4 acc[4][4] = {};

  auto stage = [&](int buf, int kt) {
    #pragma unroll
    for (int i = 0; i < 4; ++i) {
      int row = (w * 4 + i) * 8 + lrow;
      int sch = lch ^ (row & 7);
      gload16(&A[(size_t)(m0 + row) * 1024 + kt * 64 + sch * 8], &As[buf][(w * 4 + i) * 512]);
      gload16(&B[(size_t)(n0 + row) * 1024 + kt * 64 + sch * 8], &Bs[buf][(w * 4 + i) * 512]);
    }
  };

  stage(0, 0);
  __syncthreads();
  int cur = 0;

  for (int kt = 0; kt < 16; ++kt) {
    if (kt + 1 < 16) stage(cur ^ 1, kt + 1);

    const u16* as = &As[cur][0];
    const u16* bs = &Bs[cur][0];
    #pragma unroll
    for (int kh = 0; kh < 2; ++kh) {
      bf16x8 a[4], b[4];
      #pragma unroll
      for (int mi = 0; mi < 4; ++mi) {
        int row = wr * 64 + mi * 16 + lr;
        int ch = (kh * 4 + kg) ^ (lr & 7);
        a[mi] = ld8(&as[row * 64 + ch * 8]);
      }
      #pragma unroll
      for (int ni = 0; ni < 4; ++ni) {
        int row = wc * 64 + ni * 16 + lr;
        int ch = (kh * 4 + kg) ^ (lr & 7);
        b[ni] = ld8(&bs[row * 64 + ch * 8]);
      }
      #pragma unroll
      for (int mi = 0; mi < 4; ++mi)
        #pragma unroll
        for (int ni = 0; ni < 4; ++ni)
          acc[mi][ni] = MFMA(a[mi], b[ni], acc[mi][ni]);
    }

    __syncthreads();
    cur ^= 1;
  }

  #pragma unroll
  for (int mi = 0; mi < 4; ++mi) {
    #pragma unroll
    for (int ni = 0; ni < 4; ++ni) {
      int m = m0 + wr * 64 + mi * 16 + kg * 4;
      int n = n0 + wc * 64 + ni * 16 + lr;
      #pragma unroll
      for (int i = 0; i < 4; ++i)
        out[(size_t)(m + i) * D_MODEL + n] = acc[mi][ni][i];
    }
  }
}

// ---------------------------------------------------------------------------
// Kernel 2: causal flash attention — QBLK=128: 8 waves (512 thr) share each
// staged K/V tile, halving staged-tile iterations device-wide (16896->8704).
// Per-wave body is byte-identical to the proven R10/R14 structure:
// swapped-QK^T (lane holds q=lr, kv=ct*16+kg*4+i), packed b64 P-writes,
// scalar per-lane row-sum, 2-step shfl_xor reduce + per-q shuffle epilogue.
// LDS = 48 KB (K/V dbuf 32 + Ps 16) -> 3-block capacity, grid 512 = 2/CU
// (16 waves/CU, unchanged). Balance: qt2 = y<8 ? y : 23-y makes co-resident
// blocks (id, id+256) sum to ntile 36 constant. XCD pin: id%8 = bh%8.
// Mask only for kt >= ntile-2 (earlier tiles have kv_max < q0).
// ---------------------------------------------------------------------------
__global__ __launch_bounds__(512) void attn_kernel(
    const u16* __restrict__ Qb, const u16* __restrict__ Kb,
    const u16* __restrict__ Vt, u16* __restrict__ AO)
{
  __shared__ u16 Ks[2][64 * 64];   // 16 KB
  __shared__ u16 Vs[2][64 * 64];   // 16 KB  (Vs[d][kv], chunk-swizzled)
  __shared__ u16 Ps[8][16 * 64];   // 16 KB, chunk8 ^ (row&7) swizzle
  const int t = threadIdx.x;
  const int bh = blockIdx.x;       // head -> XCD = bh % 8
  const int y = blockIdx.y;        // 0..15
  const int qt2 = (y < 8) ? y : 23 - y;   // co-resident pair sums to 36 iters
  const int lane = t & 63, wv = t >> 6;   // 8 waves
  const int kg = lane >> 4, lr = lane & 15;
  const int r8 = lane >> 3, c = lane & 7;
  const int b = bh >> 4, h = bh & (NH - 1);

  // staging: wave wv stages rows [wv*8, wv*8+8) of K and V (1 load each)
  auto stage = [&](int buf, int kv0) {
    int row = wv * 8 + r8;                      // 0..63
    int sc = c ^ (row & 7);                     // pre-swizzled source chunk
    gload16(&Kb[((size_t)bh * SEQ + kv0 + row) * 64 + sc * 8], &Ks[buf][wv * 512]);
    gload16(&Vt[((size_t)bh * 64 + row) * SEQ + kv0 + sc * 8], &Vs[buf][wv * 512]);
  };

  const int ntile = 2 * qt2 + 2;
  const int q0 = qt2 * 128;
  const int qg = q0 + wv * 16 + lr;   // this lane's q row (global)

  const size_t qrow = (size_t)bh * SEQ + qg;
  bf16x8 aq0 = ld8(&Qb[qrow * 64 + kg * 8]);        // Q pre-scaled by 0.125
  bf16x8 aq1 = ld8(&Qb[qrow * 64 + 32 + kg * 8]);

  f32x4 of[4] = {};
  float rs = 0.f;

  stage(0, 0);
  int cur = 0;
  u16* ps = &Ps[wv][0];
  const int pwr = lr * 64;            // P row base (row = q local = lr)
  const int ch0 = kg ^ (lr & 7);      // chunk for k/kv 8kg..8kg+7
  const int ch1 = (4 + kg) ^ (lr & 7);

  for (int kt = 0; kt < ntile; ++kt) {
    const int kv0 = kt * 64;
    __syncthreads();               // drains staging of buf[cur]
    if (kt + 1 < ntile) stage(cur ^ 1, (kt + 1) * 64);

    // scores (swapped): S^T[kv][q] = K @ Q^T ; lane holds q=lr, kv=ct*16+kg*4+i
    const u16* kb = &Ks[cur][0];
    f32x4 sc4[4] = {};
    __builtin_amdgcn_s_setprio(1);
    #pragma unroll
    for (int ct = 0; ct < 4; ++ct) {
      sc4[ct] = MFMA(ld8(&kb[(ct * 16 + lr) * 64 + ch0 * 8]), aq0, sc4[ct]);
      sc4[ct] = MFMA(ld8(&kb[(ct * 16 + lr) * 64 + ch1 * 8]), aq1, sc4[ct]);
    }
    __builtin_amdgcn_s_setprio(0);

    // max-free softmax: P = exp(S), masked -> 0; packed b64 P-writes
    const bool domask = (kt >= ntile - 2);   // earlier tiles: kv_max < q0
    #pragma unroll
    for (int ct = 0; ct < 4; ++ct) {
      #pragma unroll
      for (int i = 0; i < 4; ++i) {
        float e = __expf(sc4[ct][i]);
        if (domask && (kv0 + ct * 16 + kg * 4 + i > qg)) e = 0.f;
        sc4[ct][i] = e;
        rs += e;
      }
      u16x4v pw = { f2bf_hw(sc4[ct][0]), f2bf_hw(sc4[ct][1]),
                    f2bf_hw(sc4[ct][2]), f2bf_hw(sc4[ct][3]) };
      // kv_local = ct*16+kg*4 -> chunk8 = 2ct+(kg>>1), offset (kg&1)*4
      *(u16x4v*)&ps[pwr + (((2 * ct + (kg >> 1)) ^ (lr & 7)) * 8 + (kg & 1) * 4)] = pw;
    }

    bf16x8 pa0 = ld8(&ps[pwr + ch0 * 8]);
    bf16x8 pa1 = ld8(&ps[pwr + ch1 * 8]);

    // PV: A = P rows q, B = Vs rows d (Vs[d][kv]) -> C row=q(kg*4+i), col=d(lr)
    const u16* vb = &Vs[cur][0];
    __builtin_amdgcn_s_setprio(1);
    #pragma unroll
    for (int vt = 0; vt < 4; ++vt) {
      of[vt] = MFMA(pa0, ld8(&vb[(vt * 16 + lr) * 64 + ch0 * 8]), of[vt]);
      of[vt] = MFMA(pa1, ld8(&vb[(vt * 16 + lr) * 64 + ch1 * 8]), of[vt]);
    }
    __builtin_amdgcn_s_setprio(0);
    cur ^= 1;
  }

  // rs: per-lane partial for q = lr; reduce across the 4 kg-groups
  rs += __shfl_xor(rs, 16, 64);
  rs += __shfl_xor(rs, 32, 64);

  // of[vt][i] is q = kg*4+i -> fetch that q's denominator from lane kg*4+i
  #pragma unroll
  for (int i = 0; i < 4; ++i) {
    float inv = 1.0f / __shfl(rs, kg * 4 + i, 64);
    int s = q0 + wv * 16 + kg * 4 + i;
    size_t base = ((size_t)(b * SEQ + s)) * D_MODEL + h * 64 + lr;
    #pragma unroll
    for (int vt = 0; vt < 4; ++vt)
      AO[base + vt * 16] = f2bf_hw(of[vt][i] * inv);
  }
}

// ---------------------------------------------------------------------------
extern "C" void kernel_launch(void* const* d_in, const int* in_sizes, int n_in,
                              void* d_out, int out_size, void* d_ws, size_t ws_size,
                              hipStream_t stream) {
  const float* X  = (const float*)d_in[0];
  const float* Wq = (const float*)d_in[1];
  const float* Wk = (const float*)d_in[2];
  const float* Wv = (const float*)d_in[3];
  const float* Wo = (const float*)d_in[4];
  float* out = (float*)d_out;

  u16* Xb = (u16*)d_ws;
  u16* Wb = Xb + (size_t)4096 * 1024;
  u16* Qb = Wb + (size_t)4096 * 1024;
  u16* Kb = Qb + (size_t)4096 * 1024;
  u16* Vt = Kb + (size_t)4096 * 1024;
  u16* AO = Vt + (size_t)4096 * 1024;

  convert_kernel<<<2048, 256, 0, stream>>>(X, Wq, Wk, Wv, Wo, Xb, Wb);
  qkv8w<<<dim3(16, 12), 512, 0, stream>>>(Xb, Wb, Qb, Kb, Vt);
  attn_kernel<<<dim3(32, 16), 512, 0, stream>>>(Qb, Kb, Vt, AO);
  oproj_kernel<<<dim3(32, 8), 256, 0, stream>>>(AO, Wb + (size_t)3 * 1024 * 1024, out);
}

// Round 16
// 99.199 us; speedup vs baseline: 1.1395x; 1.1395x over previous
//
#include <hip/hip_runtime.h>

typedef unsigned short u16;
typedef unsigned u32;
typedef __bf16 bf16x8 __attribute__((ext_vector_type(8)));
typedef float f32x4 __attribute__((ext_vector_type(4)));
typedef u16 u16x8 __attribute__((ext_vector_type(8)));
typedef u16 u16x4v __attribute__((ext_vector_type(4)));

#define D_MODEL 1024
#define SEQ 2048
#define NB 2
#define NH 16

#define MFMA(a, b, c) __builtin_amdgcn_mfma_f32_16x16x32_bf16(a, b, c, 0, 0, 0)

__device__ __forceinline__ u16 f2bf(float f) {
  unsigned u = __builtin_bit_cast(unsigned, f);
  u += 0x7FFFu + ((u >> 16) & 1u);   // round-to-nearest-even
  return (u16)(u >> 16);
}

__device__ __forceinline__ u16 f2bf_hw(float f) {
  return __builtin_bit_cast(u16, (__bf16)f);
}

__device__ __forceinline__ bf16x8 ld8(const u16* p) {
  return __builtin_bit_cast(bf16x8, *(const u16x8*)p);
}

typedef const __attribute__((address_space(1))) unsigned gu32;
typedef __attribute__((address_space(3))) unsigned lu32;
__device__ __forceinline__ void gload16(const u16* g, u16* l) {
  // async global->LDS, 16B per lane; LDS dest = wave-uniform base + lane*16
  __builtin_amdgcn_global_load_lds((gu32*)g, (lu32*)l, 16, 0, 0);
}

#define WAITV8 asm volatile("s_waitcnt vmcnt(8)" ::: "memory")
#define WAITV4 asm volatile("s_waitcnt vmcnt(4)" ::: "memory")
#define WAITV0 asm volatile("s_waitcnt vmcnt(0)" ::: "memory")
#define BARRIER __builtin_amdgcn_s_barrier()
#define SB0 __builtin_amdgcn_sched_barrier(0)

// ---------------------------------------------------------------------------
// Kernel 0: fp32 -> bf16 convert of X and all four weight matrices.
// ---------------------------------------------------------------------------
__global__ __launch_bounds__(256) void convert_kernel(
    const float* __restrict__ X, const float* __restrict__ Wq,
    const float* __restrict__ Wk, const float* __restrict__ Wv,
    const float* __restrict__ Wo, u16* __restrict__ Xb, u16* __restrict__ Wb)
{
  const int NX4 = 1024 * 1024;
  const int NW4 = 256 * 1024;
  const int TOT = NX4 + 4 * NW4;
  for (int i = blockIdx.x * 256 + threadIdx.x; i < TOT; i += gridDim.x * 256) {
    const float* src;
    u16* dst;
    if (i < NX4) {
      src = X + (size_t)i * 4;
      dst = Xb + (size_t)i * 4;
    } else {
      int j = i - NX4;
      int w = j >> 18;
      int off = j & (NW4 - 1);
      const float* ws = (w == 0) ? Wq : (w == 1) ? Wk : (w == 2) ? Wv : Wo;
      src = ws + (size_t)off * 4;
      dst = Wb + (size_t)j * 4;
    }
    float4 v = *(const float4*)src;
    u16x4v o = { f2bf(v.x), f2bf(v.y), f2bf(v.z), f2bf(v.w) };
    *(u16x4v*)dst = o;
  }
}

// ---------------------------------------------------------------------------
// Kernel 1: QKV GEMM, 256x256 tile, 8 waves, BK=32, 4-buffer LDS rotation,
// one raw s_barrier per phase, counted vmcnt(8), compact-region XCD swizzle
// (unchanged from R14 — measured best).
// ---------------------------------------------------------------------------
__global__ __launch_bounds__(512, 2) void qkv8w(
    const u16* __restrict__ A, const u16* __restrict__ B,
    u16* __restrict__ Qb, u16* __restrict__ Kb, u16* __restrict__ Vt)
{
  __shared__ u16 As[4][8192];   // 4 x 16 KB
  __shared__ u16 Bs[4][8192];   // 4 x 16 KB  -> 128 KB total
  const int t = threadIdx.x;
  const int lane = t & 63, w = t >> 6;
  const int wm = w >> 2, wn = w & 3;

  // compact-region XCD swizzle: XCD = lid%8 -> 4x6 block region
  const int lid = blockIdx.x + 16 * blockIdx.y;   // 0..191
  const int xcd = lid & 7;
  const int k = lid >> 3;                          // 0..23
  const int bx = (xcd >> 1) * 4 + (k & 3);         // 0..15
  const int by = (xcd & 1) * 6 + (k >> 2);         // 0..11

  const int m0 = bx * 256;
  const int kg = lane >> 4, lr = lane & 15;
  const int rp = lr >> 1, hf = lr & 1;
  const int xr = (((hf * 4 + kg) ^ rp) * 8);

  const int lc = (lane & 7) ^ (lane >> 3);
  const int ghalf = lc >> 2, kc = lc & 3;
  const int n0 = by * 256;

  f32x4 acc[8][4] = {};

  auto stage = [&](int buf, int kt) {
    #pragma unroll
    for (int j = 0; j < 2; ++j) {
      int g = (j * 64 + w * 8 + (lane >> 3)) * 2 + ghalf;
      gload16(&A[(size_t)(m0 + g) * 1024 + kt * 32 + kc * 8],
              &As[buf][(j * 8 + w) * 512]);
      gload16(&B[(size_t)(n0 + g) * 1024 + kt * 32 + kc * 8],
              &Bs[buf][(j * 8 + w) * 512]);
    }
  };

  auto phase = [&](int buf) {
    const u16* as = &As[buf][0];
    const u16* bs = &Bs[buf][0];
    bf16x8 a[8], b[4];
    #pragma unroll
    for (int mi = 0; mi < 8; ++mi)
      a[mi] = ld8(&as[(wm * 64 + mi * 8 + rp) * 64 + xr]);
    #pragma unroll
    for (int ni = 0; ni < 4; ++ni)
      b[ni] = ld8(&bs[(wn * 32 + ni * 8 + rp) * 64 + xr]);
    __builtin_amdgcn_s_setprio(1);
    #pragma unroll
    for (int mi = 0; mi < 8; ++mi)
      #pragma unroll
      for (int ni = 0; ni < 4; ++ni)
        acc[mi][ni] = MFMA(a[mi], b[ni], acc[mi][ni]);
    __builtin_amdgcn_s_setprio(0);
  };

  stage(0, 0);
  stage(1, 1);
  stage(2, 2);

  for (int tt = 0; tt < 28; tt += 4) {
    #pragma unroll
    for (int q = 0; q < 4; ++q) {
      const int kt = tt + q;
      WAITV8;
      BARRIER;
      SB0;
      stage((q + 3) & 3, kt + 3);
      phase(q);
    }
  }
  WAITV8; BARRIER; SB0; stage(3, 31); phase(0);
  WAITV8; BARRIER; SB0; phase(1);
  WAITV4; BARRIER; SB0; phase(2);
  WAITV0; BARRIER; SB0; phase(3);

  // epilogue: scatter to Q/K/V.  C/D frag: row = kg*4+i, col = lr.
  const int zby = by >> 2;              // 0=Q, 1=K, 2=V
  const int nl0 = (by & 3) * 256;
  const float scl = (zby == 0) ? 0.125f : 1.0f; // fold 1/sqrt(d_k) into Q
  #pragma unroll
  for (int mi = 0; mi < 8; ++mi) {
    #pragma unroll
    for (int ni = 0; ni < 4; ++ni) {
      int m = m0 + wm * 128 + mi * 16 + kg * 4;
      int nl = nl0 + wn * 64 + ni * 16 + lr;
      int bb = m >> 11, s = m & (SEQ - 1);
      int h = nl >> 6, dk = nl & 63;
      size_t bh = (size_t)(bb * NH + h);
      if (zby == 2) {
        u16x4v v = { f2bf(acc[mi][ni][0]), f2bf(acc[mi][ni][1]),
                     f2bf(acc[mi][ni][2]), f2bf(acc[mi][ni][3]) };
        *(u16x4v*)&Vt[(bh * 64 + dk) * SEQ + s] = v;
      } else {
        u16* dst = (zby == 0 ? Qb : Kb) + ((bh * SEQ + s) * 64 + dk);
        #pragma unroll
        for (int i = 0; i < 4; ++i) dst[(size_t)i * 64] = f2bf(acc[mi][ni][i] * scl);
      }
    }
  }
}

// ---------------------------------------------------------------------------
// Kernel 3: output projection — ported to the qkv8w schedule: 128x128 tile,
// 8 waves (2Mx4N, 64x32 per wave), BK=64, 16 phases, 4-buffer LDS rotation,
// one raw s_barrier per phase, counted vmcnt(8) (ledger identical to qkv8w:
// 4 loads/wave/stage; stage target (kt+3)&3 = buffer read at kt-1).
// Accumulation order over K unchanged (kt asc, kh asc) -> bitwise-same out.
// Grid 32x8 = 256 blocks = 1/CU.
// ---------------------------------------------------------------------------
__global__ __launch_bounds__(512, 2) void oproj8w(
    const u16* __restrict__ A, const u16* __restrict__ B,
    float* __restrict__ out)
{
  __shared__ u16 As[4][8192];   // 4 x 16 KB (128 rows x 64 K, chunk-XOR swz)
  __shared__ u16 Bs[4][8192];
  const int t = threadIdx.x;
  const int lane = t & 63, w = t >> 6;
  const int wm = w >> 2, wn = w & 3;      // 2 x 4 wave grid
  const int m0 = blockIdx.x * 128;
  const int n0 = blockIdx.y * 128;
  const int kg = lane >> 4, lr = lane & 15;

  // staging decode: slot j, wave w stages lds-rows (j*8+w)*8 + (lane>>3);
  // swizzled chunk = lane&7 -> logical chunk lc = (lane&7) ^ (lane>>3)
  const int srow = lane >> 3;
  const int lc = (lane & 7) ^ srow;

  f32x4 acc[4][2] = {};

  auto stage = [&](int buf, int kt) {
    #pragma unroll
    for (int j = 0; j < 2; ++j) {
      int r = (j * 8 + w) * 8 + srow;     // 0..127
      gload16(&A[(size_t)(m0 + r) * 1024 + kt * 64 + lc * 8],
              &As[buf][(j * 8 + w) * 512]);
      gload16(&B[(size_t)(n0 + r) * 1024 + kt * 64 + lc * 8],
              &Bs[buf][(j * 8 + w) * 512]);
    }
  };

  auto phase = [&](int buf) {
    const u16* as = &As[buf][0];
    const u16* bs = &Bs[buf][0];
    #pragma unroll
    for (int kh = 0; kh < 2; ++kh) {
      bf16x8 a[4], b[2];
      #pragma unroll
      for (int mi = 0; mi < 4; ++mi) {
        int row = wm * 64 + mi * 16 + lr;
        int ch = (kh * 4 + kg) ^ (row & 7);
        a[mi] = ld8(&as[row * 64 + ch * 8]);
      }
      #pragma unroll
      for (int ni = 0; ni < 2; ++ni) {
        int row = wn * 32 + ni * 16 + lr;
        int ch = (kh * 4 + kg) ^ (row & 7);
        b[ni] = ld8(&bs[row * 64 + ch * 8]);
      }
      __builtin_amdgcn_s_setprio(1);
      #pragma unroll
      for (int mi = 0; mi < 4; ++mi)
        #pragma unroll
        for (int ni = 0; ni < 2; ++ni)
          acc[mi][ni] = MFMA(a[mi], b[ni], acc[mi][ni]);
      __builtin_amdgcn_s_setprio(0);
    }
  };

  stage(0, 0);
  stage(1, 1);
  stage(2, 2);

  for (int tt = 0; tt < 12; tt += 4) {
    #pragma unroll
    for (int q = 0; q < 4; ++q) {
      const int kt = tt + q;
      WAITV8;
      BARRIER;
      SB0;
      stage((q + 3) & 3, kt + 3);
      phase(q);
    }
  }
  WAITV8; BARRIER; SB0; stage(3, 15); phase(0);
  WAITV8; BARRIER; SB0; phase(1);
  WAITV4; BARRIER; SB0; phase(2);
  WAITV0; BARRIER; SB0; phase(3);

  #pragma unroll
  for (int mi = 0; mi < 4; ++mi)
    #pragma unroll
    for (int ni = 0; ni < 2; ++ni) {
      int m = m0 + wm * 64 + mi * 16 + kg * 4;
      int n = n0 + wn * 32 + ni * 16 + lr;
      #pragma unroll
      for (int i = 0; i < 4; ++i)
        out[(size_t)(m + i) * D_MODEL + n] = acc[mi][ni][i];
    }
}

// ---------------------------------------------------------------------------
// Kernel 2: causal flash attention — EXACT R10/R14 state (measured best:
// 41.2 us). Swapped-QK^T (S^T = K@Q^T): lane holds q=lr, kv=ct*16+kg*4+i ->
// 4 packed ds_write_b64 P-writes, scalar per-lane row-sum, 2-step shfl_xor
// reduce + per-q shuffle in epilogue. KVBLK=64, double-buffered K/V via
// global_load_lds + XOR swizzle, 40 KB LDS (4 blocks/CU), head pinned to
// XCD bh%8, qt = 31-blockIdx.y (longest first).
// ---------------------------------------------------------------------------
__global__ __launch_bounds__(256) void attn_kernel(
    const u16* __restrict__ Qb, const u16* __restrict__ Kb,
    const u16* __restrict__ Vt, u16* __restrict__ AO)
{
  __shared__ u16 Ks[2][64 * 64];   // 16 KB
  __shared__ u16 Vs[2][64 * 64];   // 16 KB  (Vs[d][kv], chunk-swizzled)
  __shared__ u16 Ps[4][16 * 64];   // 8 KB, chunk8 ^ (row&7) swizzle
  const int t = threadIdx.x;
  const int bh = blockIdx.x;       // head -> XCD = bh % 8
  const int qt = 31 - blockIdx.y;  // longest first
  const int lane = t & 63, wv = t >> 6;
  const int kg = lane >> 4, lr = lane & 15;
  const int r8 = lane >> 3, c = lane & 7;
  const int b = bh >> 4, h = bh & (NH - 1);

  auto stage = [&](int buf, int kv0) {
    #pragma unroll
    for (int i = 0; i < 2; ++i) {
      int s = wv * 2 + i;
      int row = s * 8 + r8;                       // 0..63
      int sc = c ^ (row & 7);                     // pre-swizzled source chunk
      gload16(&Kb[((size_t)bh * SEQ + kv0 + row) * 64 + sc * 8], &Ks[buf][s * 512]);
      gload16(&Vt[((size_t)bh * 64 + row) * SEQ + kv0 + sc * 8], &Vs[buf][s * 512]);
    }
  };

  const int ntile = qt + 1;
  const int q0 = qt * 64;
  const int qg = q0 + wv * 16 + lr;   // this lane's q row (global)

  const size_t qrow = (size_t)bh * SEQ + qg;
  bf16x8 aq0 = ld8(&Qb[qrow * 64 + kg * 8]);        // Q pre-scaled by 0.125
  bf16x8 aq1 = ld8(&Qb[qrow * 64 + 32 + kg * 8]);

  f32x4 of[4] = {};
  float rs = 0.f;

  stage(0, 0);
  int cur = 0;
  u16* ps = &Ps[wv][0];
  const int pwr = lr * 64;            // P row base (row = q local = lr)
  const int ch0 = kg ^ (lr & 7);      // chunk for k/kv 8kg..8kg+7
  const int ch1 = (4 + kg) ^ (lr & 7);

  for (int kt = 0; kt < ntile; ++kt) {
    const int kv0 = kt * 64;
    __syncthreads();               // drains staging of buf[cur]
    if (kt + 1 < ntile) stage(cur ^ 1, (kt + 1) * 64);

    // scores (swapped): S^T[kv][q] = K @ Q^T ; lane holds q=lr, kv=ct*16+kg*4+i
    const u16* kb = &Ks[cur][0];
    f32x4 sc4[4] = {};
    __builtin_amdgcn_s_setprio(1);
    #pragma unroll
    for (int ct = 0; ct < 4; ++ct) {
      sc4[ct] = MFMA(ld8(&kb[(ct * 16 + lr) * 64 + ch0 * 8]), aq0, sc4[ct]);
      sc4[ct] = MFMA(ld8(&kb[(ct * 16 + lr) * 64 + ch1 * 8]), aq1, sc4[ct]);
    }
    __builtin_amdgcn_s_setprio(0);

    // max-free softmax: P = exp(S), masked -> 0; packed b64 P-writes
    const bool domask = (kt == ntile - 1);
    #pragma unroll
    for (int ct = 0; ct < 4; ++ct) {
      #pragma unroll
      for (int i = 0; i < 4; ++i) {
        float e = __expf(sc4[ct][i]);
        if (domask && (kv0 + ct * 16 + kg * 4 + i > qg)) e = 0.f;
        sc4[ct][i] = e;
        rs += e;
      }
      u16x4v pw = { f2bf_hw(sc4[ct][0]), f2bf_hw(sc4[ct][1]),
                    f2bf_hw(sc4[ct][2]), f2bf_hw(sc4[ct][3]) };
      // kv_local = ct*16+kg*4 -> chunk8 = 2ct+(kg>>1), offset (kg&1)*4
      *(u16x4v*)&ps[pwr + (((2 * ct + (kg >> 1)) ^ (lr & 7)) * 8 + (kg & 1) * 4)] = pw;
    }

    bf16x8 pa0 = ld8(&ps[pwr + ch0 * 8]);
    bf16x8 pa1 = ld8(&ps[pwr + ch1 * 8]);

    // PV: A = P rows q, B = Vs rows d (Vs[d][kv]) -> C row=q(kg*4+i), col=d(lr)
    const u16* vb = &Vs[cur][0];
    __builtin_amdgcn_s_setprio(1);
    #pragma unroll
    for (int vt = 0; vt < 4; ++vt) {
      of[vt] = MFMA(pa0, ld8(&vb[(vt * 16 + lr) * 64 + ch0 * 8]), of[vt]);
      of[vt] = MFMA(pa1, ld8(&vb[(vt * 16 + lr) * 64 + ch1 * 8]), of[vt]);
    }
    __builtin_amdgcn_s_setprio(0);
    cur ^= 1;
  }

  // rs: per-lane partial for q = lr; reduce across the 4 kg-groups
  rs += __shfl_xor(rs, 16, 64);
  rs += __shfl_xor(rs, 32, 64);

  // of[vt][i] is q = kg*4+i -> fetch that q's denominator from lane kg*4+i
  #pragma unroll
  for (int i = 0; i < 4; ++i) {
    float inv = 1.0f / __shfl(rs, kg * 4 + i, 64);
    int s = q0 + wv * 16 + kg * 4 + i;
    size_t base = ((size_t)(b * SEQ + s)) * D_MODEL + h * 64 + lr;
    #pragma unroll
    for (int vt = 0; vt < 4; ++vt)
      AO[base + vt * 16] = f2bf_hw(of[vt][i] * inv);
  }
}

// ---------------------------------------------------------------------------
extern "C" void kernel_launch(void* const* d_in, const int* in_sizes, int n_in,
                              void* d_out, int out_size, void* d_ws, size_t ws_size,
                              hipStream_t stream) {
  const float* X  = (const float*)d_in[0];
  const float* Wq = (const float*)d_in[1];
  const float* Wk = (const float*)d_in[2];
  const float* Wv = (const float*)d_in[3];
  const float* Wo = (const float*)d_in[4];
  float* out = (float*)d_out;

  u16* Xb = (u16*)d_ws;
  u16* Wb = Xb + (size_t)4096 * 1024;
  u16* Qb = Wb + (size_t)4096 * 1024;
  u16* Kb = Qb + (size_t)4096 * 1024;
  u16* Vt = Kb + (size_t)4096 * 1024;
  u16* AO = Vt + (size_t)4096 * 1024;

  convert_kernel<<<2048, 256, 0, stream>>>(X, Wq, Wk, Wv, Wo, Xb, Wb);
  qkv8w<<<dim3(16, 12), 512, 0, stream>>>(Xb, Wb, Qb, Kb, Vt);
  attn_kernel<<<dim3(32, 32), 256, 0, stream>>>(Qb, Kb, Vt, AO);
  oproj8w<<<dim3(32, 8), 512, 0, stream>>>(AO, Wb + (size_t)3 * 1024 * 1024, out);
}

// Round 17
// 98.741 us; speedup vs baseline: 1.1447x; 1.0046x over previous
//
#include <hip/hip_runtime.h>

typedef unsigned short u16;
typedef unsigned u32;
typedef __bf16 bf16x8 __attribute__((ext_vector_type(8)));
typedef float f32x4 __attribute__((ext_vector_type(4)));
typedef u16 u16x8 __attribute__((ext_vector_type(8)));
typedef u16 u16x4v __attribute__((ext_vector_type(4)));

#define D_MODEL 1024
#define SEQ 2048
#define NB 2
#define NH 16

#define MFMA(a, b, c) __builtin_amdgcn_mfma_f32_16x16x32_bf16(a, b, c, 0, 0, 0)

__device__ __forceinline__ u16 f2bf(float f) {
  unsigned u = __builtin_bit_cast(unsigned, f);
  u += 0x7FFFu + ((u >> 16) & 1u);   // round-to-nearest-even
  return (u16)(u >> 16);
}

__device__ __forceinline__ u16 f2bf_hw(float f) {
  return __builtin_bit_cast(u16, (__bf16)f);
}

__device__ __forceinline__ bf16x8 ld8(const u16* p) {
  return __builtin_bit_cast(bf16x8, *(const u16x8*)p);
}

typedef const __attribute__((address_space(1))) unsigned gu32;
typedef __attribute__((address_space(3))) unsigned lu32;
__device__ __forceinline__ void gload16(const u16* g, u16* l) {
  // async global->LDS, 16B per lane; LDS dest = wave-uniform base + lane*16
  __builtin_amdgcn_global_load_lds((gu32*)g, (lu32*)l, 16, 0, 0);
}

#define WAITV8 asm volatile("s_waitcnt vmcnt(8)" ::: "memory")
#define WAITV4 asm volatile("s_waitcnt vmcnt(4)" ::: "memory")
#define WAITV0 asm volatile("s_waitcnt vmcnt(0)" ::: "memory")
#define BARRIER __builtin_amdgcn_s_barrier()
#define SB0 __builtin_amdgcn_sched_barrier(0)

// ---------------------------------------------------------------------------
// Kernel 0: fp32 -> bf16 convert of X and all four weight matrices.
// ---------------------------------------------------------------------------
__global__ __launch_bounds__(256) void convert_kernel(
    const float* __restrict__ X, const float* __restrict__ Wq,
    const float* __restrict__ Wk, const float* __restrict__ Wv,
    const float* __restrict__ Wo, u16* __restrict__ Xb, u16* __restrict__ Wb)
{
  const int NX4 = 1024 * 1024;
  const int NW4 = 256 * 1024;
  const int TOT = NX4 + 4 * NW4;
  for (int i = blockIdx.x * 256 + threadIdx.x; i < TOT; i += gridDim.x * 256) {
    const float* src;
    u16* dst;
    if (i < NX4) {
      src = X + (size_t)i * 4;
      dst = Xb + (size_t)i * 4;
    } else {
      int j = i - NX4;
      int w = j >> 18;
      int off = j & (NW4 - 1);
      const float* ws = (w == 0) ? Wq : (w == 1) ? Wk : (w == 2) ? Wv : Wo;
      src = ws + (size_t)off * 4;
      dst = Wb + (size_t)j * 4;
    }
    float4 v = *(const float4*)src;
    u16x4v o = { f2bf(v.x), f2bf(v.y), f2bf(v.z), f2bf(v.w) };
    *(u16x4v*)dst = o;
  }
}

// ---------------------------------------------------------------------------
// Kernel 1: QKV GEMM, 256x256 tile, 8 waves, BK=32, 4-buffer LDS rotation,
// one raw s_barrier per phase, counted vmcnt(8), compact-region XCD swizzle
// (unchanged from R14 — measured best).
// ---------------------------------------------------------------------------
__global__ __launch_bounds__(512, 2) void qkv8w(
    const u16* __restrict__ A, const u16* __restrict__ B,
    u16* __restrict__ Qb, u16* __restrict__ Kb, u16* __restrict__ Vt)
{
  __shared__ u16 As[4][8192];   // 4 x 16 KB
  __shared__ u16 Bs[4][8192];   // 4 x 16 KB  -> 128 KB total
  const int t = threadIdx.x;
  const int lane = t & 63, w = t >> 6;
  const int wm = w >> 2, wn = w & 3;

  // compact-region XCD swizzle: XCD = lid%8 -> 4x6 block region
  const int lid = blockIdx.x + 16 * blockIdx.y;   // 0..191
  const int xcd = lid & 7;
  const int k = lid >> 3;                          // 0..23
  const int bx = (xcd >> 1) * 4 + (k & 3);         // 0..15
  const int by = (xcd & 1) * 6 + (k >> 2);         // 0..11

  const int m0 = bx * 256;
  const int kg = lane >> 4, lr = lane & 15;
  const int rp = lr >> 1, hf = lr & 1;
  const int xr = (((hf * 4 + kg) ^ rp) * 8);

  const int lc = (lane & 7) ^ (lane >> 3);
  const int ghalf = lc >> 2, kc = lc & 3;
  const int n0 = by * 256;

  f32x4 acc[8][4] = {};

  auto stage = [&](int buf, int kt) {
    #pragma unroll
    for (int j = 0; j < 2; ++j) {
      int g = (j * 64 + w * 8 + (lane >> 3)) * 2 + ghalf;
      gload16(&A[(size_t)(m0 + g) * 1024 + kt * 32 + kc * 8],
              &As[buf][(j * 8 + w) * 512]);
      gload16(&B[(size_t)(n0 + g) * 1024 + kt * 32 + kc * 8],
              &Bs[buf][(j * 8 + w) * 512]);
    }
  };

  auto phase = [&](int buf) {
    const u16* as = &As[buf][0];
    const u16* bs = &Bs[buf][0];
    bf16x8 a[8], b[4];
    #pragma unroll
    for (int mi = 0; mi < 8; ++mi)
      a[mi] = ld8(&as[(wm * 64 + mi * 8 + rp) * 64 + xr]);
    #pragma unroll
    for (int ni = 0; ni < 4; ++ni)
      b[ni] = ld8(&bs[(wn * 32 + ni * 8 + rp) * 64 + xr]);
    __builtin_amdgcn_s_setprio(1);
    #pragma unroll
    for (int mi = 0; mi < 8; ++mi)
      #pragma unroll
      for (int ni = 0; ni < 4; ++ni)
        acc[mi][ni] = MFMA(a[mi], b[ni], acc[mi][ni]);
    __builtin_amdgcn_s_setprio(0);
  };

  stage(0, 0);
  stage(1, 1);
  stage(2, 2);

  for (int tt = 0; tt < 28; tt += 4) {
    #pragma unroll
    for (int q = 0; q < 4; ++q) {
      const int kt = tt + q;
      WAITV8;
      BARRIER;
      SB0;
      stage((q + 3) & 3, kt + 3);
      phase(q);
    }
  }
  WAITV8; BARRIER; SB0; stage(3, 31); phase(0);
  WAITV8; BARRIER; SB0; phase(1);
  WAITV4; BARRIER; SB0; phase(2);
  WAITV0; BARRIER; SB0; phase(3);

  // epilogue: scatter to Q/K/V.  C/D frag: row = kg*4+i, col = lr.
  const int zby = by >> 2;              // 0=Q, 1=K, 2=V
  const int nl0 = (by & 3) * 256;
  const float scl = (zby == 0) ? 0.125f : 1.0f; // fold 1/sqrt(d_k) into Q
  #pragma unroll
  for (int mi = 0; mi < 8; ++mi) {
    #pragma unroll
    for (int ni = 0; ni < 4; ++ni) {
      int m = m0 + wm * 128 + mi * 16 + kg * 4;
      int nl = nl0 + wn * 64 + ni * 16 + lr;
      int bb = m >> 11, s = m & (SEQ - 1);
      int h = nl >> 6, dk = nl & 63;
      size_t bh = (size_t)(bb * NH + h);
      if (zby == 2) {
        u16x4v v = { f2bf(acc[mi][ni][0]), f2bf(acc[mi][ni][1]),
                     f2bf(acc[mi][ni][2]), f2bf(acc[mi][ni][3]) };
        *(u16x4v*)&Vt[(bh * 64 + dk) * SEQ + s] = v;
      } else {
        u16* dst = (zby == 0 ? Qb : Kb) + ((bh * SEQ + s) * 64 + dk);
        #pragma unroll
        for (int i = 0; i < 4; ++i) dst[(size_t)i * 64] = f2bf(acc[mi][ni][i] * scl);
      }
    }
  }
}

// ---------------------------------------------------------------------------
// Kernel 3: output projection — qkv8w schedule: 128x128 tile, 8 waves,
// BK=64, 16 phases, 4-buffer LDS rotation, counted vmcnt(8) (unchanged
// from R16 — measured improvement).
// ---------------------------------------------------------------------------
__global__ __launch_bounds__(512, 2) void oproj8w(
    const u16* __restrict__ A, const u16* __restrict__ B,
    float* __restrict__ out)
{
  __shared__ u16 As[4][8192];   // 4 x 16 KB (128 rows x 64 K, chunk-XOR swz)
  __shared__ u16 Bs[4][8192];
  const int t = threadIdx.x;
  const int lane = t & 63, w = t >> 6;
  const int wm = w >> 2, wn = w & 3;      // 2 x 4 wave grid
  const int m0 = blockIdx.x * 128;
  const int n0 = blockIdx.y * 128;
  const int kg = lane >> 4, lr = lane & 15;

  const int srow = lane >> 3;
  const int lc = (lane & 7) ^ srow;

  f32x4 acc[4][2] = {};

  auto stage = [&](int buf, int kt) {
    #pragma unroll
    for (int j = 0; j < 2; ++j) {
      int r = (j * 8 + w) * 8 + srow;     // 0..127
      gload16(&A[(size_t)(m0 + r) * 1024 + kt * 64 + lc * 8],
              &As[buf][(j * 8 + w) * 512]);
      gload16(&B[(size_t)(n0 + r) * 1024 + kt * 64 + lc * 8],
              &Bs[buf][(j * 8 + w) * 512]);
    }
  };

  auto phase = [&](int buf) {
    const u16* as = &As[buf][0];
    const u16* bs = &Bs[buf][0];
    #pragma unroll
    for (int kh = 0; kh < 2; ++kh) {
      bf16x8 a[4], b[2];
      #pragma unroll
      for (int mi = 0; mi < 4; ++mi) {
        int row = wm * 64 + mi * 16 + lr;
        int ch = (kh * 4 + kg) ^ (row & 7);
        a[mi] = ld8(&as[row * 64 + ch * 8]);
      }
      #pragma unroll
      for (int ni = 0; ni < 2; ++ni) {
        int row = wn * 32 + ni * 16 + lr;
        int ch = (kh * 4 + kg) ^ (row & 7);
        b[ni] = ld8(&bs[row * 64 + ch * 8]);
      }
      __builtin_amdgcn_s_setprio(1);
      #pragma unroll
      for (int mi = 0; mi < 4; ++mi)
        #pragma unroll
        for (int ni = 0; ni < 2; ++ni)
          acc[mi][ni] = MFMA(a[mi], b[ni], acc[mi][ni]);
      __builtin_amdgcn_s_setprio(0);
    }
  };

  stage(0, 0);
  stage(1, 1);
  stage(2, 2);

  for (int tt = 0; tt < 12; tt += 4) {
    #pragma unroll
    for (int q = 0; q < 4; ++q) {
      const int kt = tt + q;
      WAITV8;
      BARRIER;
      SB0;
      stage((q + 3) & 3, kt + 3);
      phase(q);
    }
  }
  WAITV8; BARRIER; SB0; stage(3, 15); phase(0);
  WAITV8; BARRIER; SB0; phase(1);
  WAITV4; BARRIER; SB0; phase(2);
  WAITV0; BARRIER; SB0; phase(3);

  #pragma unroll
  for (int mi = 0; mi < 4; ++mi)
    #pragma unroll
    for (int ni = 0; ni < 2; ++ni) {
      int m = m0 + wm * 64 + mi * 16 + kg * 4;
      int n = n0 + wn * 32 + ni * 16 + lr;
      #pragma unroll
      for (int i = 0; i < 4; ++i)
        out[(size_t)(m + i) * D_MODEL + n] = acc[mi][ni][i];
    }
}

// ---------------------------------------------------------------------------
// Kernel 2: causal flash attention — R10/R16 body, SINGLE CHANGE: balanced
// qt remap. Co-resident family on one CU = {y, y+8, y+16, y+24} (blocks
// id, id+256, id+512, id+768 share a CU; all 1024 blocks resident at t=0).
// qt map {y0, 15-y0, 16+y0, 31-y0} makes every family's ntile sum exactly
// 66 (was 52..80 under qt=31-y). XCD pin id%8 = bh%8 unchanged.
// ---------------------------------------------------------------------------
__global__ __launch_bounds__(256) void attn_kernel(
    const u16* __restrict__ Qb, const u16* __restrict__ Kb,
    const u16* __restrict__ Vt, u16* __restrict__ AO)
{
  __shared__ u16 Ks[2][64 * 64];   // 16 KB
  __shared__ u16 Vs[2][64 * 64];   // 16 KB  (Vs[d][kv], chunk-swizzled)
  __shared__ u16 Ps[4][16 * 64];   // 8 KB, chunk8 ^ (row&7) swizzle
  const int t = threadIdx.x;
  const int bh = blockIdx.x;       // head -> XCD = bh % 8
  const int y = blockIdx.y;
  // balanced remap: family {y0, y0+8, y0+16, y0+24} -> qt {y0,15-y0,16+y0,31-y0}
  const int qt = (y < 8) ? y : (y < 16) ? (23 - y) : (y < 24) ? y : (55 - y);
  const int lane = t & 63, wv = t >> 6;
  const int kg = lane >> 4, lr = lane & 15;
  const int r8 = lane >> 3, c = lane & 7;
  const int b = bh >> 4, h = bh & (NH - 1);

  auto stage = [&](int buf, int kv0) {
    #pragma unroll
    for (int i = 0; i < 2; ++i) {
      int s = wv * 2 + i;
      int row = s * 8 + r8;                       // 0..63
      int sc = c ^ (row & 7);                     // pre-swizzled source chunk
      gload16(&Kb[((size_t)bh * SEQ + kv0 + row) * 64 + sc * 8], &Ks[buf][s * 512]);
      gload16(&Vt[((size_t)bh * 64 + row) * SEQ + kv0 + sc * 8], &Vs[buf][s * 512]);
    }
  };

  const int ntile = qt + 1;
  const int q0 = qt * 64;
  const int qg = q0 + wv * 16 + lr;   // this lane's q row (global)

  const size_t qrow = (size_t)bh * SEQ + qg;
  bf16x8 aq0 = ld8(&Qb[qrow * 64 + kg * 8]);        // Q pre-scaled by 0.125
  bf16x8 aq1 = ld8(&Qb[qrow * 64 + 32 + kg * 8]);

  f32x4 of[4] = {};
  float rs = 0.f;

  stage(0, 0);
  int cur = 0;
  u16* ps = &Ps[wv][0];
  const int pwr = lr * 64;            // P row base (row = q local = lr)
  const int ch0 = kg ^ (lr & 7);      // chunk for k/kv 8kg..8kg+7
  const int ch1 = (4 + kg) ^ (lr & 7);

  for (int kt = 0; kt < ntile; ++kt) {
    const int kv0 = kt * 64;
    __syncthreads();               // drains staging of buf[cur]
    if (kt + 1 < ntile) stage(cur ^ 1, (kt + 1) * 64);

    // scores (swapped): S^T[kv][q] = K @ Q^T ; lane holds q=lr, kv=ct*16+kg*4+i
    const u16* kb = &Ks[cur][0];
    f32x4 sc4[4] = {};
    __builtin_amdgcn_s_setprio(1);
    #pragma unroll
    for (int ct = 0; ct < 4; ++ct) {
      sc4[ct] = MFMA(ld8(&kb[(ct * 16 + lr) * 64 + ch0 * 8]), aq0, sc4[ct]);
      sc4[ct] = MFMA(ld8(&kb[(ct * 16 + lr) * 64 + ch1 * 8]), aq1, sc4[ct]);
    }
    __builtin_amdgcn_s_setprio(0);

    // max-free softmax: P = exp(S), masked -> 0; packed b64 P-writes
    const bool domask = (kt == ntile - 1);
    #pragma unroll
    for (int ct = 0; ct < 4; ++ct) {
      #pragma unroll
      for (int i = 0; i < 4; ++i) {
        float e = __expf(sc4[ct][i]);
        if (domask && (kv0 + ct * 16 + kg * 4 + i > qg)) e = 0.f;
        sc4[ct][i] = e;
        rs += e;
      }
      u16x4v pw = { f2bf_hw(sc4[ct][0]), f2bf_hw(sc4[ct][1]),
                    f2bf_hw(sc4[ct][2]), f2bf_hw(sc4[ct][3]) };
      // kv_local = ct*16+kg*4 -> chunk8 = 2ct+(kg>>1), offset (kg&1)*4
      *(u16x4v*)&ps[pwr + (((2 * ct + (kg >> 1)) ^ (lr & 7)) * 8 + (kg & 1) * 4)] = pw;
    }

    bf16x8 pa0 = ld8(&ps[pwr + ch0 * 8]);
    bf16x8 pa1 = ld8(&ps[pwr + ch1 * 8]);

    // PV: A = P rows q, B = Vs rows d (Vs[d][kv]) -> C row=q(kg*4+i), col=d(lr)
    const u16* vb = &Vs[cur][0];
    __builtin_amdgcn_s_setprio(1);
    #pragma unroll
    for (int vt = 0; vt < 4; ++vt) {
      of[vt] = MFMA(pa0, ld8(&vb[(vt * 16 + lr) * 64 + ch0 * 8]), of[vt]);
      of[vt] = MFMA(pa1, ld8(&vb[(vt * 16 + lr) * 64 + ch1 * 8]), of[vt]);
    }
    __builtin_amdgcn_s_setprio(0);
    cur ^= 1;
  }

  // rs: per-lane partial for q = lr; reduce across the 4 kg-groups
  rs += __shfl_xor(rs, 16, 64);
  rs += __shfl_xor(rs, 32, 64);

  // of[vt][i] is q = kg*4+i -> fetch that q's denominator from lane kg*4+i
  #pragma unroll
  for (int i = 0; i < 4; ++i) {
    float inv = 1.0f / __shfl(rs, kg * 4 + i, 64);
    int s = q0 + wv * 16 + kg * 4 + i;
    size_t base = ((size_t)(b * SEQ + s)) * D_MODEL + h * 64 + lr;
    #pragma unroll
    for (int vt = 0; vt < 4; ++vt)
      AO[base + vt * 16] = f2bf_hw(of[vt][i] * inv);
  }
}

// ---------------------------------------------------------------------------
extern "C" void kernel_launch(void* const* d_in, const int* in_sizes, int n_in,
                              void* d_out, int out_size, void* d_ws, size_t ws_size,
                              hipStream_t stream) {
  const float* X  = (const float*)d_in[0];
  const float* Wq = (const float*)d_in[1];
  const float* Wk = (const float*)d_in[2];
  const float* Wv = (const float*)d_in[3];
  const float* Wo = (const float*)d_in[4];
  float* out = (float*)d_out;

  u16* Xb = (u16*)d_ws;
  u16* Wb = Xb + (size_t)4096 * 1024;
  u16* Qb = Wb + (size_t)4096 * 1024;
  u16* Kb = Qb + (size_t)4096 * 1024;
  u16* Vt = Kb + (size_t)4096 * 1024;
  u16* AO = Vt + (size_t)4096 * 1024;

  convert_kernel<<<2048, 256, 0, stream>>>(X, Wq, Wk, Wv, Wo, Xb, Wb);
  qkv8w<<<dim3(16, 12), 512, 0, stream>>>(Xb, Wb, Qb, Kb, Vt);
  attn_kernel<<<dim3(32, 32), 256, 0, stream>>>(Qb, Kb, Vt, AO);
  oproj8w<<<dim3(32, 8), 512, 0, stream>>>(AO, Wb + (size_t)3 * 1024 * 1024, out);
}